// Round 5
// baseline (296.941 us; speedup 1.0000x reference)
//
#include <hip/hip_runtime.h>
#include <cstdint>
#include <cstddef>

// All external tensors are FP32 (per reference). Internals use bf16 for MFMA.
typedef unsigned short u16;
typedef __attribute__((ext_vector_type(4))) float f32x4;
typedef __attribute__((ext_vector_type(8))) __bf16 bf16x8;
typedef __attribute__((ext_vector_type(4))) __bf16 bf16x4;
typedef __attribute__((ext_vector_type(8))) unsigned short u16x8;

#define DEV static __device__ __forceinline__

#if __has_builtin(__builtin_amdgcn_exp2f)
#define EXP2(x) __builtin_amdgcn_exp2f(x)
#else
#define EXP2(x) exp2f(x)
#endif

DEV float bf2f(u16 v) { return __uint_as_float(((unsigned)v) << 16); }
DEV u16 f2bf(float f) {
  unsigned u = __float_as_uint(f);
  return (u16)((u + 0x7FFFu + ((u >> 16) & 1u)) >> 16);
}

DEV void gl_lds16(const void* g, void* l) {
  __builtin_amdgcn_global_load_lds((const __attribute__((address_space(1))) void*)g,
                                   (__attribute__((address_space(3))) void*)l, 16, 0, 0);
}

// ---------------------------------------------------------------------------
// Fused W transpose (Wq | Wkv) + fp32->bf16: bt rows 0..1023 = Wq^T,
// rows 1024..1535 = Wkv^T. grid = (16, 24): by<16 -> Wq col-block, else Wkv.
__global__ __launch_bounds__(256) void trans_qkv_w(const float* __restrict__ Wq,
                                                   const float* __restrict__ Wkv,
                                                   u16* __restrict__ bt) {
  __shared__ __attribute__((aligned(16))) u16 t[64 * 72];
  const int r0 = blockIdx.x * 64, tid = threadIdx.x;
  const int by = blockIdx.y;
  const float* in;
  int incols, c0;
  u16* out;
  if (by < 16) { in = Wq; incols = 1024; c0 = by * 64; out = bt; }
  else { in = Wkv; incols = 512; c0 = (by - 16) * 64; out = bt + 1024 * 1024; }
#pragma unroll
  for (int i = 0; i < 2; i++) {
    int c = i * 256 + tid;
    int row = c >> 3, cc = c & 7;
    const float* src = &in[(size_t)(r0 + row) * incols + c0 + cc * 8];
    f32x4 v0 = *(const f32x4*)src;
    f32x4 v1 = *(const f32x4*)(src + 4);
    u16x8 o;
#pragma unroll
    for (int j = 0; j < 4; j++) { o[j] = f2bf(v0[j]); o[4 + j] = f2bf(v1[j]); }
    *(u16x8*)&t[row * 72 + cc * 8] = o;
  }
  __syncthreads();
#pragma unroll
  for (int i = 0; i < 2; i++) {
    int c = i * 256 + tid;
    int d = c >> 3, nc = c & 7;
    u16x8 o;
#pragma unroll
    for (int j = 0; j < 8; j++) o[j] = t[(nc * 8 + j) * 72 + d];
    *(u16x8*)&out[(size_t)(c0 + d) * 1024 + r0 + nc * 8] = o;
  }
}

// Single-matrix 64x64 transpose (for Wout). grid = (16, 16).
__global__ __launch_bounds__(256) void transpose64(const float* __restrict__ in,
                                                   u16* __restrict__ out, int incols) {
  __shared__ __attribute__((aligned(16))) u16 t[64 * 72];
  const int r0 = blockIdx.x * 64, c0 = blockIdx.y * 64, tid = threadIdx.x;
#pragma unroll
  for (int i = 0; i < 2; i++) {
    int c = i * 256 + tid;
    int row = c >> 3, cc = c & 7;
    const float* src = &in[(size_t)(r0 + row) * incols + c0 + cc * 8];
    f32x4 v0 = *(const f32x4*)src;
    f32x4 v1 = *(const f32x4*)(src + 4);
    u16x8 o;
#pragma unroll
    for (int j = 0; j < 4; j++) { o[j] = f2bf(v0[j]); o[4 + j] = f2bf(v1[j]); }
    *(u16x8*)&t[row * 72 + cc * 8] = o;
  }
  __syncthreads();
#pragma unroll
  for (int i = 0; i < 2; i++) {
    int c = i * 256 + tid;
    int d = c >> 3, nc = c & 7;
    u16x8 o;
#pragma unroll
    for (int j = 0; j < 8; j++) o[j] = t[(nc * 8 + j) * 72 + d];
    *(u16x8*)&out[(size_t)(c0 + d) * 1024 + r0 + nc * 8] = o;
  }
}

// ---------------------------------------------------------------------------
// LayerNorm over DIM=1024 (fp32 in, bf16 out), one block per row.
__global__ __launch_bounds__(256) void ln_x(const float* __restrict__ x,
                                            const float* __restrict__ sc,
                                            const float* __restrict__ bi,
                                            u16* __restrict__ xn) {
  __shared__ float red[8];
  const int row = blockIdx.x, tid = threadIdx.x;
  const int w = tid >> 6;
  f32x4 f = *(const f32x4*)&x[(size_t)row * 1024 + tid * 4];
  float s = f[0] + f[1] + f[2] + f[3];
  float q = f[0] * f[0] + f[1] * f[1] + f[2] * f[2] + f[3] * f[3];
#pragma unroll
  for (int off = 1; off < 64; off <<= 1) {
    s += __shfl_xor(s, off);
    q += __shfl_xor(q, off);
  }
  if ((tid & 63) == 0) { red[w] = s; red[4 + w] = q; }
  __syncthreads();
  float S = red[0] + red[1] + red[2] + red[3];
  float Q = red[4] + red[5] + red[6] + red[7];
  float mu = S * (1.0f / 1024.0f);
  float var = Q * (1.0f / 1024.0f) - mu * mu;
  float rs = rsqrtf(var + 1e-6f);
  f32x4 scv = *(const f32x4*)&sc[tid * 4];
  f32x4 biv = *(const f32x4*)&bi[tid * 4];
  u16* o = xn + (size_t)row * 1024 + tid * 4;
#pragma unroll
  for (int j = 0; j < 4; j++) o[j] = f2bf((f[j] - mu) * rs * scv[j] + biv[j]);
}

// ---------------------------------------------------------------------------
// C[M][N] = A[M][K] * Bt[N][K]^T, bf16 in; out bf16 or fp32 (F32OUT).
// 128x128 tile, BK=64, XOR-swizzled LDS (chunk c of row r at slot c^(r&7)).
template <bool F32OUT>
__global__ __launch_bounds__(256) void gemm_bt(const u16* __restrict__ A,
                                               const u16* __restrict__ Bt,
                                               void* __restrict__ Cp,
                                               int M, int N, int K) {
  __shared__ __attribute__((aligned(16))) u16 Als[128 * 64];
  __shared__ __attribute__((aligned(16))) u16 Bls[128 * 64];
  const int tid = threadIdx.x;
  const int w = tid >> 6, lane = tid & 63, ln = lane & 15, quad = lane >> 4;
  const int m0 = blockIdx.y * 128, n0 = blockIdx.x * 128;
  const int moff = (w & 1) * 64, noff = (w >> 1) * 64;
  const f32x4 fzero = {0.f, 0.f, 0.f, 0.f};
  f32x4 acc[4][4];
#pragma unroll
  for (int i = 0; i < 4; i++)
#pragma unroll
    for (int j = 0; j < 4; j++) acc[i][j] = fzero;

  const u16* aS[4];
  const u16* bS[4];
#pragma unroll
  for (int i = 0; i < 4; i++) {
    int s = i * 256 + tid;
    int row = s >> 3, cs = (s & 7) ^ (row & 7);
    aS[i] = A + (size_t)(m0 + row) * K + cs * 8;
    bS[i] = Bt + (size_t)(n0 + row) * K + cs * 8;
  }

  for (int k0 = 0; k0 < K; k0 += 64) {
    __syncthreads();
#pragma unroll
    for (int i = 0; i < 4; i++) {
      int s = i * 256 + tid;
      gl_lds16(aS[i] + k0, &Als[s * 8]);
      gl_lds16(bS[i] + k0, &Bls[s * 8]);
    }
    __syncthreads();
#pragma unroll
    for (int kk = 0; kk < 2; kk++) {
      bf16x8 af[4], bfv[4];
#pragma unroll
      for (int mi = 0; mi < 4; mi++)
        af[mi] = *(const bf16x8*)
            &Als[(moff + mi * 16 + ln) * 64 + (((kk * 4 + quad) ^ (ln & 7)) * 8)];
#pragma unroll
      for (int ni = 0; ni < 4; ni++)
        bfv[ni] = *(const bf16x8*)
            &Bls[(noff + ni * 16 + ln) * 64 + (((kk * 4 + quad) ^ (ln & 7)) * 8)];
#pragma unroll
      for (int mi = 0; mi < 4; mi++)
#pragma unroll
        for (int ni = 0; ni < 4; ni++)
          acc[mi][ni] = __builtin_amdgcn_mfma_f32_16x16x32_bf16(af[mi], bfv[ni],
                                                                acc[mi][ni], 0, 0, 0);
    }
  }
#pragma unroll
  for (int mi = 0; mi < 4; mi++)
#pragma unroll
    for (int ni = 0; ni < 4; ni++)
#pragma unroll
      for (int r = 0; r < 4; r++) {
        size_t m = m0 + moff + mi * 16 + quad * 4 + r;
        size_t n = n0 + noff + ni * 16 + ln;
        if (F32OUT)
          ((float*)Cp)[m * N + n] = acc[mi][ni][r];
        else
          ((u16*)Cp)[m * N + n] = f2bf(acc[mi][ni][r]);
      }
}

// ---------------------------------------------------------------------------
// Fused post-QKV: blocks [0,8192) do per-head LN of q,k (Q pre-scaled by
// 0.125*log2e, fixed-max softmax safe); blocks [8192,8704) transpose V.
__global__ __launch_bounds__(256) void qkv_post(const u16* __restrict__ qkv,
                                                const float* __restrict__ qs,
                                                const float* __restrict__ qb,
                                                const float* __restrict__ ks,
                                                const float* __restrict__ kb,
                                                u16* __restrict__ Q,
                                                u16* __restrict__ Kb,
                                                u16* __restrict__ Vt) {
  __shared__ __attribute__((aligned(16))) u16 t[64 * 72];
  const int bid = blockIdx.x;
  const int tid = threadIdx.x;
  if (bid < 8192) {
    const float SCL = 0.18033688011112042f;  // 0.125 * log2(e)
    const int b = bid >> 11, n = bid & 2047;
    const int w = tid >> 6, lane = tid & 63;
    const u16* rowp = qkv + (size_t)bid * 1536;
    const float qsc = qs[lane], qbi = qb[lane];
    const float ksc = ks[lane], kbi = kb[lane];
#pragma unroll
    for (int i = 0; i < 4; i++) {
      int h = w * 4 + i;
      float v = bf2f(rowp[h * 64 + lane]);
      float s = v, q2 = v * v;
#pragma unroll
      for (int off = 1; off < 64; off <<= 1) {
        s += __shfl_xor(s, off);
        q2 += __shfl_xor(q2, off);
      }
      float mu = s * (1.0f / 64.0f);
      float var = q2 * (1.0f / 64.0f) - mu * mu;
      float y = ((v - mu) * rsqrtf(var + 1e-6f) * qsc + qbi) * SCL;
      Q[((size_t)(b * 16 + h) * 2048 + n) * 64 + lane] = f2bf(y);
    }
    {
      int g = w;
      float v = bf2f(rowp[1024 + g * 64 + lane]);
      float s = v, q2 = v * v;
#pragma unroll
      for (int off = 1; off < 64; off <<= 1) {
        s += __shfl_xor(s, off);
        q2 += __shfl_xor(q2, off);
      }
      float mu = s * (1.0f / 64.0f);
      float var = q2 * (1.0f / 64.0f) - mu * mu;
      float y = (v - mu) * rsqrtf(var + 1e-6f) * ksc + kbi;
      Kb[((size_t)(b * 4 + g) * 2048 + n) * 64 + lane] = f2bf(y);
    }
  } else {
    const int idx = bid - 8192;
    const int n0 = (idx & 31) * 64;
    const int bg = idx >> 5;
    const int b = bg >> 2, g = bg & 3;
    const u16* src = qkv + (size_t)(b * 2048 + n0) * 1536 + 1280 + g * 64;
#pragma unroll
    for (int i = 0; i < 2; i++) {
      int c = i * 256 + tid;
      int row = c >> 3, cc = c & 7;
      *(f32x4*)&t[row * 72 + cc * 8] = *(const f32x4*)&src[(size_t)row * 1536 + cc * 8];
    }
    __syncthreads();
    u16* dst = Vt + (size_t)bg * 64 * 2048 + n0;
#pragma unroll
    for (int i = 0; i < 2; i++) {
      int c = i * 256 + tid;
      int d = c >> 3, nc = c & 7;
      u16x8 o;
#pragma unroll
      for (int j = 0; j < 8; j++) o[j] = t[(nc * 8 + j) * 72 + d];
      *(u16x8*)&dst[(size_t)d * 2048 + nc * 8] = o;
    }
  }
}

// ---------------------------------------------------------------------------
// Flash attention, transposed-S, fixed-max softmax, KT=64 keys/iter,
// q-tile = 64 (16 rows/wave). grid = (32, 64), block = 256 (4 waves).
// LDS = 24 KB (K 8K + V 8K + P 8K) -> 5-6 blocks/CU co-resident.
// All kt-invariant LDS offsets hoisted; launch_bounds(256,5) -> <=102 VGPR.
__global__ __launch_bounds__(256, 5) void attn(const u16* __restrict__ Q,
                                               const u16* __restrict__ Kb,
                                               const u16* __restrict__ Vt,
                                               u16* __restrict__ Out) {
  __shared__ __attribute__((aligned(16))) u16 Kls[64 * 64];     // [key][d]
  __shared__ __attribute__((aligned(16))) u16 Vls[64 * 64];     // [d][key]
  __shared__ __attribute__((aligned(16))) u16 Pls[4][16 * 64];  // per-wave [m][key]
  const int qt = blockIdx.x;
  const int bh = blockIdx.y;
  const int b = bh >> 4, h = bh & 15, g = h >> 2;
  const int tid = threadIdx.x, w = tid >> 6, lane = tid & 63;
  const int ln = lane & 15, quad = lane >> 4;
  const u16* Qg = Q + ((size_t)(b * 16 + h) * 2048 + qt * 64 + w * 16) * 64;
  const u16* Kg = Kb + (size_t)(b * 4 + g) * 2048 * 64;
  const u16* Vg = Vt + (size_t)(b * 4 + g) * 64 * 2048;
  const f32x4 fzero = {0.f, 0.f, 0.f, 0.f};

  // Q fragment (B-operand): row m = ln, k(d) = ks2*32 + quad*8
  bf16x8 qf[2];
#pragma unroll
  for (int ks2 = 0; ks2 < 2; ks2++)
    qf[ks2] = *(const bf16x8*)&Qg[(size_t)ln * 64 + ks2 * 32 + quad * 8];

  f32x4 oacc[4];
#pragma unroll
  for (int ni = 0; ni < 4; ni++) oacc[ni] = fzero;
  float lsum = 0.f;
  u16* Pw = &Pls[w][0];

  // hoisted kt-invariant geometry ------------------------------------------
  // staging (2 chunks per thread per buffer)
  const int sk0 = tid, sk1 = 256 + tid;
  const int krow0 = sk0 >> 3, kcs0 = (sk0 & 7) ^ (krow0 & 7);
  const int krow1 = sk1 >> 3, kcs1 = (sk1 & 7) ^ (krow1 & 7);
  const u16* kp0 = Kg + (size_t)krow0 * 64 + kcs0 * 8;
  const u16* kp1 = Kg + (size_t)krow1 * 64 + kcs1 * 8;
  const u16* vp0 = Vg + (size_t)krow0 * 2048 + kcs0 * 8;
  const u16* vp1 = Vg + (size_t)krow1 * 2048 + kcs1 * 8;
  u16* kd0 = &Kls[sk0 * 8];
  u16* kd1 = &Kls[sk1 * 8];
  u16* vd0 = &Vls[sk0 * 8];
  u16* vd1 = &Vls[sk1 * 8];
  // K fragment read offsets (elements)
  int koffA[4], koffB[4], vroff[4][2];
#pragma unroll
  for (int ni = 0; ni < 4; ni++) {
    const int row = ni * 16 + ln;
    koffA[ni] = row * 64 + ((quad ^ (ln & 7)) * 8);
    koffB[ni] = row * 64 + (((4 + quad) ^ (ln & 7)) * 8);
#pragma unroll
    for (int kc = 0; kc < 2; kc++)
      vroff[ni][kc] = row * 64 + (((4 * kc + quad) ^ (ln & 7)) * 8);
  }
  // P store byte offsets / read offsets
  char* pst[4];
#pragma unroll
  for (int ni = 0; ni < 4; ni++)
    pst[ni] = (char*)Pw + ln * 128 + (((2 * ni + (quad >> 1)) ^ (ln & 7)) * 16) +
              ((quad & 1) * 8);
  int proff[2];
#pragma unroll
  for (int kc = 0; kc < 2; kc++)
    proff[kc] = ln * 64 + (((4 * kc + quad) ^ (ln & 7)) * 8);
  // -------------------------------------------------------------------------

  for (int kt = 0; kt < 32; kt++) {
    __syncthreads();
    gl_lds16(kp0, kd0);
    gl_lds16(kp1, kd1);
    gl_lds16(vp0, vd0);
    gl_lds16(vp1, vd1);
    kp0 += 64 * 64; kp1 += 64 * 64;
    vp0 += 64; vp1 += 64;
    __syncthreads();

    // S^T: sacc[ni][r] = S[key=ni*16+quad*4+r][m=ln]  (exp2 domain)
    f32x4 sacc[4];
#pragma unroll
    for (int ni = 0; ni < 4; ni++) {
      bf16x8 kf0 = *(const bf16x8*)&Kls[koffA[ni]];
      bf16x8 kf1 = *(const bf16x8*)&Kls[koffB[ni]];
      f32x4 tt = __builtin_amdgcn_mfma_f32_16x16x32_bf16(kf0, qf[0], fzero, 0, 0, 0);
      sacc[ni] = __builtin_amdgcn_mfma_f32_16x16x32_bf16(kf1, qf[1], tt, 0, 0, 0);
    }

    // fixed-max softmax: p = exp2(s); row sums per-lane (row m = ln)
    float ls = 0.f;
#pragma unroll
    for (int ni = 0; ni < 4; ni++) {
      float p0 = EXP2(sacc[ni][0]);
      float p1 = EXP2(sacc[ni][1]);
      float p2 = EXP2(sacc[ni][2]);
      float p3 = EXP2(sacc[ni][3]);
      ls += (p0 + p1) + (p2 + p3);
      bf16x4 pv = {(__bf16)p0, (__bf16)p1, (__bf16)p2, (__bf16)p3};
      *(bf16x4*)pst[ni] = pv;
    }
    ls += __shfl_xor(ls, 16);
    ls += __shfl_xor(ls, 32);
    lsum += ls;

    // O^T += Vt * P^T  (A = V rows d, B = P cols m); Pw is wave-private.
#pragma unroll
    for (int kc = 0; kc < 2; kc++) {
      bf16x8 pf = *(const bf16x8*)&Pw[proff[kc]];
#pragma unroll
      for (int ni = 0; ni < 4; ni++) {
        bf16x8 vf = *(const bf16x8*)&Vls[vroff[ni][kc]];
        oacc[ni] = __builtin_amdgcn_mfma_f32_16x16x32_bf16(vf, pf, oacc[ni], 0, 0, 0);
      }
    }
  }

  // epilogue: O[m][d] = O^T / lsum; row n = qt*64 + w*16 + ln
  const float inv = 1.0f / lsum;
  u16* Og = Out + ((size_t)b * 2048 + qt * 64 + w * 16 + ln) * 1024 + h * 64;
#pragma unroll
  for (int ni = 0; ni < 4; ni++) {
    bf16x4 ov = {(__bf16)(oacc[ni][0] * inv), (__bf16)(oacc[ni][1] * inv),
                 (__bf16)(oacc[ni][2] * inv), (__bf16)(oacc[ni][3] * inv)};
    *(bf16x4*)&Og[ni * 16 + quad * 4] = ov;
  }
}

// ---------------------------------------------------------------------------
extern "C" void kernel_launch(void* const* d_in, const int* in_sizes, int n_in,
                              void* d_out, int out_size, void* d_ws, size_t ws_size,
                              hipStream_t stream) {
  const float* x    = (const float*)d_in[0];
  const float* lns  = (const float*)d_in[1];
  const float* lnb  = (const float*)d_in[2];
  const float* Wq   = (const float*)d_in[3];
  const float* Wkv  = (const float*)d_in[4];
  const float* qns  = (const float*)d_in[5];
  const float* qnb  = (const float*)d_in[6];
  const float* kns  = (const float*)d_in[7];
  const float* knb  = (const float*)d_in[8];
  const float* Wout = (const float*)d_in[9];
  float* out = (float*)d_out;
  char* ws = (char*)d_ws;

  const size_t o_xn  = 0;                 // 16 MB: xn (bf16), later Qbuf
  const size_t o_qkv = 16777216;          // 24 MB: qkv (bf16), later attn_out
  const size_t o_bt  = o_qkv + 25165824;  // 3 MB: W^T (bf16), reused for Wout^T
  const size_t o_k   = o_bt + 3145728;    // 4 MB: Kbuf
  const size_t o_vt  = o_k + 4194304;     // 4 MB: Vtbuf
  u16* xn   = (u16*)(ws + o_xn);
  u16* qkv  = (u16*)(ws + o_qkv);
  u16* bt   = (u16*)(ws + o_bt);
  u16* Kbuf = (u16*)(ws + o_k);
  u16* Vtb  = (u16*)(ws + o_vt);
  u16* Qbuf = xn;    // xn dead after GEMM1
  u16* aout = qkv;   // qkv dead after qkv_post

  trans_qkv_w<<<dim3(16, 24), 256, 0, stream>>>(Wq, Wkv, bt);
  ln_x<<<8192, 256, 0, stream>>>(x, lns, lnb, xn);
  gemm_bt<false><<<dim3(12, 64), 256, 0, stream>>>(xn, bt, qkv, 8192, 1536, 1024);
  transpose64<<<dim3(16, 16), 256, 0, stream>>>(Wout, bt, 1024);
  qkv_post<<<8704, 256, 0, stream>>>(qkv, qns, qnb, kns, knb, Qbuf, Kbuf, Vtb);
  attn<<<dim3(32, 64), 256, 0, stream>>>(Qbuf, Kbuf, Vtb, aout);
  gemm_bt<true><<<dim3(8, 64), 256, 0, stream>>>(aout, bt, out, 8192, 1024, 1024);

  (void)in_sizes; (void)n_in; (void)out_size; (void)ws_size;
}